// Round 9
// baseline (162.281 us; speedup 1.0000x reference)
//
#include <hip/hip_runtime.h>
#include <hip/hip_bf16.h>

#define EDIM 256
#define TDIM 1024
#define NHEAD 8
#define HDIM 32
#define NBATCH 8
#define NBH 64
#define INV_LN2 1.4426950408889634f
#define SCALE2 (0.17677669529663687f * 1.4426950408889634f)  // hd^-0.5 / ln2

typedef __attribute__((ext_vector_type(8))) short short8;
typedef __attribute__((ext_vector_type(4))) short short4v;
typedef __attribute__((ext_vector_type(4))) float f32x4;

__device__ __forceinline__ f32x4 mfma16(short8 a, short8 b, f32x4 c) {
  return __builtin_amdgcn_mfma_f32_16x16x32_bf16(a, b, c, 0, 0, 0);
}
__device__ __forceinline__ float bf2f(short h) {
  return __uint_as_float(((unsigned)(unsigned short)h) << 16);
}
__device__ __forceinline__ short f2bf1(float x) {
  unsigned u = __float_as_uint(x);
  u = (u + 0x7fffu + ((u >> 16) & 1u)) >> 16;
  return (short)u;
}
__device__ __forceinline__ short4v packbf4(float a, float b, float c, float d) {
  __hip_bfloat162 x = __float22bfloat162_rn(make_float2(a, b));
  __hip_bfloat162 y = __float22bfloat162_rn(make_float2(c, d));
  unsigned ux, uy;
  __builtin_memcpy(&ux, &x, 4);
  __builtin_memcpy(&uy, &y, 4);
  short4v r;
  r[0] = (short)(ux & 0xffffu); r[1] = (short)(ux >> 16);
  r[2] = (short)(uy & 0xffffu); r[3] = (short)(uy >> 16);
  return r;
}
// Raw v_exp_f32 (no libm denorm/range fixup). Valid: args statically
// bounded ~15 << 126. (R4 ablation: halved VALUBusy, time ~flat -> kernel
// is VMEM-bound, not VALU-bound.)
__device__ __forceinline__ float fexp2(float x) {
#if __has_builtin(__builtin_amdgcn_exp2f)
  return __builtin_amdgcn_exp2f(x);
#else
  return exp2f(x);
#endif
}

// ---------------------------------------------------------------------------
// prepare (2048 blocks):
//   blk 0..255   : split 4 weight mats -> bf16 hi/lo
//   blk 256..511 : mask[t][s] -> maskS[s/4][t][4] * INV_LN2 (LDS transpose,
//                  writes 1 KB-contiguous per wave)
//   blk 512..2047: split q/k/v [B][E][T] fp32 -> Xs[tensor][b][t][e] bf16 hi
//                  (LDS transpose; both global phases coalesced)
// ---------------------------------------------------------------------------
__global__ __launch_bounds__(256) void prepare(
    const float* __restrict__ w0, const float* __restrict__ w1,
    const float* __restrict__ w2, const float* __restrict__ w3,
    const float* __restrict__ mask, const float* __restrict__ qin,
    const float* __restrict__ kin, const float* __restrict__ vin,
    short* __restrict__ wsp, float* __restrict__ maskS,
    short* __restrict__ Xs)
{
  const int blk = blockIdx.x;
  const int tid = threadIdx.x;
  __shared__ float Tl[64][65];

  if (blk < 256) {
    const int z = blk >> 6, chunk = blk & 63;
    const float* W = (z == 0) ? w0 : (z == 1) ? w1 : (z == 2) ? w2 : w3;
    short* hi = wsp + (size_t)z * 2 * EDIM * EDIM;
    short* lo = hi + EDIM * EDIM;
    const int idx = chunk * 1024 + tid * 4;
    float4 v = *(const float4*)&W[idx];
    short4v h = packbf4(v.x, v.y, v.z, v.w);
    short4v l = packbf4(v.x - bf2f(h[0]), v.y - bf2f(h[1]),
                        v.z - bf2f(h[2]), v.w - bf2f(h[3]));
    *(short4v*)&hi[idx] = h;
    *(short4v*)&lo[idx] = l;
  } else if (blk < 512) {
    const int i = blk - 256;
    const int t0 = (i >> 4) * 64, s0 = (i & 15) * 64;
    const int r = tid >> 2, c = (tid & 3) * 16;
#pragma unroll
    for (int g = 0; g < 4; ++g) {
      float4 v = *(const float4*)&mask[(size_t)(t0 + r) * TDIM + s0 + c + 4 * g];
      Tl[c + 4 * g + 0][r] = v.x * INV_LN2;
      Tl[c + 4 * g + 1][r] = v.y * INV_LN2;
      Tl[c + 4 * g + 2][r] = v.z * INV_LN2;
      Tl[c + 4 * g + 3][r] = v.w * INV_LN2;
    }
    __syncthreads();
    const int sql = tid >> 6, tl = tid & 63;
#pragma unroll
    for (int g = 0; g < 4; ++g) {
      const int sq = g * 4 + sql;       // s-quad within tile, 0..15
      float4 o;
      o.x = Tl[sq * 4 + 0][tl];
      o.y = Tl[sq * 4 + 1][tl];
      o.z = Tl[sq * 4 + 2][tl];
      o.w = Tl[sq * 4 + 3][tl];
      *(float4*)&maskS[(size_t)(s0 / 4 + sq) * 4096 + (size_t)(t0 + tl) * 4] = o;
    }
  } else {
    const int bz = blk - 512;
    const int tt = bz & 15, ee = (bz >> 4) & 3, tb = bz >> 6;  // tb 0..23
    const float* src = ((tb >> 3) == 0) ? qin : ((tb >> 3) == 1) ? kin : vin;
    const int b = tb & 7;
    const int t0 = tt * 64, e0 = ee * 64;
    const float* s = src + (size_t)b * EDIM * TDIM;
    const int tl = tid & 63, er = (tid >> 6) * 16;
#pragma unroll
    for (int i = 0; i < 16; ++i)
      Tl[tl][er + i] = s[(size_t)(e0 + er + i) * TDIM + t0 + tl];
    __syncthreads();
    const int rt = tid >> 2, seg = (tid & 3) * 16;
    float v[16];
#pragma unroll
    for (int i = 0; i < 16; ++i) v[i] = Tl[rt][seg + i];
    short* dst = Xs + ((size_t)tb * TDIM + t0 + rt) * EDIM + e0 + seg;
#pragma unroll
    for (int i = 0; i < 4; ++i)
      *(short4v*)&dst[4 * i] =
          packbf4(v[4 * i], v[4 * i + 1], v[4 * i + 2], v[4 * i + 3]);
  }
}

// ---------------------------------------------------------------------------
// proj: C = W @ X + bias, X [.][t][e] bf16, W bf16 hi/lo. 64m x 64n block,
// K=256 whole: W-frags in registers, X staged as one flat 32 KB XOR-swizzled
// copy -> single barrier. 2-pass split MFMA.
// tensor: 0=Q ([bh][t][d] bf16, *SCALE2), 1=K hi/lo, 2=V ([bh][d][t] bf16),
// 3=final (fp32 [b][E][T]).
// R9: for tensor==3 the X-stage is replaced by a FUSED MERGE of the 4 flash
// partial planes (merge4 kernel deleted): stage reads pq0..3 [b*256+e][t]
// bf16 (coalesced 128B runs along t), multiplies by 1/sum(Lh) from a 2 KB
// LDS table, scatters into the same swizzled Xl. Math order identical to
// old merge4 -> bit-identical output. pp3 must NOT overlay d_out (fused
// kernel writes Of while other blocks read pp3) -> moved to workspace.
// ---------------------------------------------------------------------------
__global__ __launch_bounds__(256, 4) void proj(
    const short* __restrict__ Xbase, const short* __restrict__ wsp,
    const float* __restrict__ b0, const float* __restrict__ b1,
    const float* __restrict__ b2, const float* __restrict__ b3,
    short* __restrict__ Qt, short* __restrict__ KtHi, short* __restrict__ KtLo,
    short* __restrict__ VHi, float* __restrict__ Of, int tbase,
    const unsigned short* __restrict__ pq0, const unsigned short* __restrict__ pq1,
    const unsigned short* __restrict__ pq2, const unsigned short* __restrict__ pq3,
    const float* __restrict__ LhP)
{
  const int z = blockIdx.z;
  const int tloc = z >> 3;
  const int tensor = tbase + tloc;
  const int batch = z & 7;
  const int m0 = blockIdx.y * 64;
  const int n0 = blockIdx.x * 64;
  const int tid = threadIdx.x;
  const int w = tid >> 6, lane = tid & 63, q = lane >> 4, l16 = lane & 15;

  const float* bias = (tensor == 0) ? b0 : (tensor == 1) ? b1
                      : (tensor == 2) ? b2 : b3;
  const short* Wh = wsp + (size_t)tensor * 2 * EDIM * EDIM;
  const short* Wl = Wh + EDIM * EDIM;
  const short* Xt = Xbase + ((size_t)(tloc * NBATCH + batch) * TDIM + n0) * EDIM;

  __shared__ __align__(16) short Xl[64 * 256];  // 32 KB, XOR-swizzled [t][e]
  __shared__ float invL[8][64];                 // 2 KB (tensor==3 only)

  short8 ah[8], al[8];
  {
    const short* wrh = Wh + (size_t)(m0 + 16 * w + l16) * EDIM + q * 8;
    const short* wrl = Wl + (size_t)(m0 + 16 * w + l16) * EDIM + q * 8;
#pragma unroll
    for (int c = 0; c < 8; ++c) {
      ah[c] = *(const short8*)&wrh[c * 32];
      al[c] = *(const short8*)&wrl[c * 32];
    }
  }
  if (tensor == 3) {
    // ---- fused merge4: Xl[t][e] = (sum_q partials) / (sum_q l) ----
    for (int i = tid; i < 512; i += 256) {
      const int h8 = i >> 6, t = i & 63;
      const size_t lo = (size_t)(batch * NHEAD + h8) * TDIM + n0 + t;
      const float l = LhP[lo] + LhP[65536 + lo] + LhP[131072 + lo] +
                      LhP[196608 + lo];
      invL[h8][t] = 1.f / l;
    }
    __syncthreads();
#pragma unroll
    for (int itr = 0; itr < 8; ++itr) {
      const int pos = itr * 256 + tid;
      const int e = pos >> 3, t8 = pos & 7;
      const size_t o = ((size_t)batch * 256 + e) * TDIM + n0 + t8 * 8;
      short8 a0 = *(const short8*)&pq0[o];
      short8 a1 = *(const short8*)&pq1[o];
      short8 a2 = *(const short8*)&pq2[o];
      short8 a3 = *(const short8*)&pq3[o];
      const int e8 = e >> 3, eb7 = e & 7, h8 = e >> 5;
#pragma unroll
      for (int j = 0; j < 8; ++j) {
        const float v = (bf2f(a0[j]) + bf2f(a1[j]) + bf2f(a2[j]) + bf2f(a3[j]))
                        * invL[h8][t8 * 8 + j];
        Xl[(t8 * 8 + j) * 256 + ((e8 ^ j) << 3) + eb7] = f2bf1(v);
      }
    }
  } else {
#pragma unroll
    for (int k2 = 0; k2 < 8; ++k2) {
      const int tl = k2 * 8 + (tid >> 5);
      const int e8 = tid & 31;
      short8 vv = *(const short8*)&Xt[(size_t)k2 * 2048 + tid * 8];
      *(short8*)&Xl[tl * 256 + ((e8 ^ (tl & 7)) << 3)] = vv;
    }
  }
  __syncthreads();

  f32x4 acc[4] = {};
  const int lm = l16 & 7;
#pragma unroll
  for (int c = 0; c < 8; ++c) {
#pragma unroll
    for (int j = 0; j < 4; ++j) {
      short8 bf = *(const short8*)&Xl[(16 * j + l16) * 256 +
                                      (((c * 4 + q) ^ lm) << 3)];
      acc[j] = mfma16(ah[c], bf, acc[j]);
      acc[j] = mfma16(al[c], bf, acc[j]);
    }
  }

  if (tensor == 3) {
#pragma unroll
    for (int j = 0; j < 4; ++j) {
      const int n = n0 + 16 * j + l16;
#pragma unroll
      for (int r = 0; r < 4; ++r) {
        const int m = m0 + 16 * w + 4 * q + r;
        Of[((size_t)batch * EDIM + m) * TDIM + n] = acc[j][r] + bias[m];
      }
    }
    return;
  }
  if (tensor == 2) {
#pragma unroll
    for (int j = 0; j < 4; ++j) {
      const int n = n0 + 16 * j + l16;
#pragma unroll
      for (int r = 0; r < 4; ++r) {
        const int m = m0 + 16 * w + 4 * q + r;
        VHi[((size_t)batch * EDIM + m) * TDIM + n] = f2bf1(acc[j][r] + bias[m]);
      }
    }
    return;
  }
  __syncthreads();
  float (*Lt)[68] = (float (*)[68])Xl;  // 17408 B <= 32768
#pragma unroll
  for (int j = 0; j < 4; ++j) {
    const int mb = m0 + 16 * w + 4 * q;
    float4 v4;
    v4.x = acc[j][0] + bias[mb + 0];
    v4.y = acc[j][1] + bias[mb + 1];
    v4.z = acc[j][2] + bias[mb + 2];
    v4.w = acc[j][3] + bias[mb + 3];
    if (tensor == 0) { v4.x *= SCALE2; v4.y *= SCALE2; v4.z *= SCALE2; v4.w *= SCALE2; }
    *(float4*)&Lt[16 * j + l16][16 * w + 4 * q] = v4;
  }
  __syncthreads();
  {
    const int tl = tid >> 2;
    const int seg = (tid & 3) * 16;
    const int ch = m0 + seg;
    const int bh = batch * NHEAD + (ch >> 5);
    const int d0 = ch & 31;
    const size_t o = ((size_t)bh * TDIM + n0 + tl) * HDIM + d0;
    float v[16];
#pragma unroll
    for (int i = 0; i < 16; ++i) v[i] = Lt[tl][seg + i];
    if (tensor == 0) {
#pragma unroll
      for (int i = 0; i < 4; ++i)
        *(short4v*)&Qt[o + 4 * i] =
            packbf4(v[4 * i], v[4 * i + 1], v[4 * i + 2], v[4 * i + 3]);
    } else {
#pragma unroll
      for (int i = 0; i < 4; ++i) {
        short4v h = packbf4(v[4 * i], v[4 * i + 1], v[4 * i + 2], v[4 * i + 3]);
        short4v l = packbf4(v[4 * i + 0] - bf2f(h[0]), v[4 * i + 1] - bf2f(h[1]),
                            v[4 * i + 2] - bf2f(h[2]), v[4 * i + 3] - bf2f(h[3]));
        *(short4v*)&KtHi[o + 4 * i] = h;
        *(short4v*)&KtLo[o + 4 * i] = l;
      }
    }
  }
}

// ---------------------------------------------------------------------------
// flash6: transposed flash, s-split x4, NO max-tracking (scores statically
// bounded). p = exp2(s+m), l = sum(p); O stored UNNORMALIZED bf16 + l per
// quarter. Ps SINGLE-buffered (per-wave, DS in-order -> WAR-safe).
// K hi/lo staged in LDS once per block (R8: 4x K request-traffic cut, the
// biggest flash6 win). Mask (64x bh-redundant, not block-shareable) and V
// stay as hoisted register loads. LDS 50 KB -> 3 blocks/CU.
// History: (256,8) spills; (256,5)/(256,3) alone no-op; setprio -5us;
// fexp2 VALU 37->20% time-neutral; 20-load hoist -6%; +fence 0%;
// K-LDS -10% (47->42.6).
// ---------------------------------------------------------------------------
__global__ __launch_bounds__(256, 3) void flash6(
    const short* __restrict__ Qt, const short* __restrict__ KtHi,
    const short* __restrict__ KtLo, const short* __restrict__ VHi,
    const float* __restrict__ maskS, unsigned short* __restrict__ p0,
    unsigned short* __restrict__ p1, unsigned short* __restrict__ p2,
    unsigned short* __restrict__ p3, float* __restrict__ Lh)
{
  const int tid = threadIdx.x;
  const int w = tid >> 6, lane = tid & 63, q = lane >> 4, l16 = lane & 15;
  const int bh = blockIdx.x;
  const int t0 = blockIdx.y * 128 + w * 32;
  const int quarter = blockIdx.z;
  const int sbase = quarter * 256;

  __shared__ __align__(16) short KhS[8192];      // K hi [256 s][32 d], 16 KB
  __shared__ __align__(16) short KlS[8192];      // K lo, 16 KB
  __shared__ __align__(16) short Ps[4][32][72];  // per-wave P^T, 18 KB

  // ---- cooperative K stage: all 4 waves share one copy (4x traffic cut).
  {
    const short* kgh = KtHi + (size_t)bh * TDIM * HDIM + (size_t)sbase * HDIM;
    const short* kgl = KtLo + (size_t)bh * TDIM * HDIM + (size_t)sbase * HDIM;
#pragma unroll
    for (int r = 0; r < 4; ++r) {
      *(short8*)&KhS[r * 2048 + tid * 8] =
          *(const short8*)&kgh[r * 2048 + tid * 8];
      *(short8*)&KlS[r * 2048 + tid * 8] =
          *(const short8*)&kgl[r * 2048 + tid * 8];
    }
  }

  const short* qb = Qt + (size_t)bh * TDIM * HDIM;
  const short* vh_p = VHi + (size_t)bh * HDIM * TDIM +
                      (size_t)l16 * TDIM + sbase + q * 8;
  const float* m_p = maskS + ((size_t)(sbase >> 2) + q) * 4096 +
                     (size_t)(t0 + l16) * 4;

  short8 qf0 = *(const short8*)&qb[(size_t)(t0 + l16) * HDIM + q * 8];
  short8 qf1 = *(const short8*)&qb[(size_t)(t0 + 16 + l16) * HDIM + q * 8];

  __syncthreads();  // K staged; no further barriers (Ps is per-wave)

  float ls[2] = {0.f, 0.f};
  f32x4 oacc[2][2] = {};  // [d-tile][nt]

#pragma unroll
  for (int it = 0; it < 4; ++it) {
    const short* vh_i = vh_p + it * 64;
    const float* m_i = m_p + it * 65536;

    // ---- issue the 12 remaining VMEM loads (mask 8, V 4) up front ----
    float4 ma[4], mb[4];     // mask (= S^T init)
    short8 vv[2][2];         // V
#pragma unroll
    for (int mt = 0; mt < 4; ++mt) {
      ma[mt] = *(const float4*)(m_i + (size_t)mt * 16384);
      mb[mt] = *(const float4*)(m_i + (size_t)mt * 16384 + 64);
    }
#pragma unroll
    for (int c = 0; c < 2; ++c)
#pragma unroll
      for (int dt = 0; dt < 2; ++dt)
        vv[c][dt] = *(const short8*)(vh_i + dt * 16384 + c * 32);

    // ---- S^T = mask + K^T Q (K fragments from LDS) ----
    f32x4 sc[4][2];
#pragma unroll
    for (int mt = 0; mt < 4; ++mt) {
      sc[mt][0] = f32x4{ma[mt].x, ma[mt].y, ma[mt].z, ma[mt].w};
      sc[mt][1] = f32x4{mb[mt].x, mb[mt].y, mb[mt].z, mb[mt].w};
    }
#pragma unroll
    for (int mt = 0; mt < 4; ++mt) {
      const int srow = (64 * it + 16 * mt + l16) * 32 + q * 8;
      short8 kh = *(const short8*)&KhS[srow];
      short8 kl = *(const short8*)&KlS[srow];
      sc[mt][0] = mfma16(kh, qf0, sc[mt][0]);
      sc[mt][0] = mfma16(kl, qf0, sc[mt][0]);
      sc[mt][1] = mfma16(kh, qf1, sc[mt][1]);
      sc[mt][1] = mfma16(kl, qf1, sc[mt][1]);
    }
    // ---- p = exp2(s); tree-sum into per-lane ls ----
#pragma unroll
    for (int nt = 0; nt < 2; ++nt) {
      float p[16];
#pragma unroll
      for (int mt = 0; mt < 4; ++mt)
#pragma unroll
        for (int r = 0; r < 4; ++r) p[4 * mt + r] = fexp2(sc[mt][nt][r]);
      ls[nt] += (((p[0] + p[1]) + (p[2] + p[3])) +
                 ((p[4] + p[5]) + (p[6] + p[7]))) +
                (((p[8] + p[9]) + (p[10] + p[11])) +
                 ((p[12] + p[13]) + (p[14] + p[15])));
#pragma unroll
      for (int mt = 0; mt < 4; ++mt)
        *(short4v*)&Ps[w][16 * nt + l16][16 * mt + 4 * q] =
            packbf4(p[4 * mt], p[4 * mt + 1], p[4 * mt + 2], p[4 * mt + 3]);
    }
    // ---- O^T += V P^T (vv prefetched at iteration top) ----
#pragma unroll
    for (int c = 0; c < 2; ++c) {
      short8 pf0 = *(const short8*)&Ps[w][l16][32 * c + 8 * q];
      short8 pf1 = *(const short8*)&Ps[w][16 + l16][32 * c + 8 * q];
#pragma unroll
      for (int dt = 0; dt < 2; ++dt) {
        oacc[dt][0] = mfma16(vv[c][dt], pf0, oacc[dt][0]);
        oacc[dt][1] = mfma16(vv[c][dt], pf1, oacc[dt][1]);
      }
    }
  }

  ls[0] += __shfl_xor(ls[0], 16);
  ls[0] += __shfl_xor(ls[0], 32);
  ls[1] += __shfl_xor(ls[1], 16);
  ls[1] += __shfl_xor(ls[1], 32);

  unsigned short* Op = (quarter == 0) ? p0 : (quarter == 1) ? p1
                       : (quarter == 2) ? p2 : p3;
#pragma unroll
  for (int nt = 0; nt < 2; ++nt) {
    const int t = t0 + 16 * nt + l16;
#pragma unroll
    for (int dt = 0; dt < 2; ++dt)
#pragma unroll
      for (int r = 0; r < 4; ++r) {
        const int d = 16 * dt + 4 * q + r;
        Op[((size_t)bh * HDIM + d) * TDIM + t] =
            (unsigned short)f2bf1(oacc[dt][nt][r]);  // unnormalized
      }
    if (q == 0)
      Lh[(size_t)quarter * NBH * TDIM + (size_t)bh * TDIM + t] = ls[nt];
  }
}

// ---------------------------------------------------------------------------
extern "C" void kernel_launch(void* const* d_in, const int* in_sizes, int n_in,
                              void* d_out, int out_size, void* d_ws, size_t ws_size,
                              hipStream_t stream)
{
  const float* query = (const float*)d_in[0];
  const float* key   = (const float*)d_in[1];
  const float* value = (const float*)d_in[2];
  const float* msk   = (const float*)d_in[3];
  const float* Wq = (const float*)d_in[4];
  const float* Wk = (const float*)d_in[5];
  const float* Wv = (const float*)d_in[6];
  const float* Wo = (const float*)d_in[7];
  const float* bq = (const float*)d_in[8];
  const float* bk = (const float*)d_in[9];
  const float* bv = (const float*)d_in[10];
  const float* bo = (const float*)d_in[11];
  float* out = (float*)d_out;

  const size_t PL = (size_t)NBATCH * TDIM * EDIM;  // 2M elements
  short* Xs    = (short*)d_ws;            // 3 planes bf16 [tensor][b][t][e]
  short* Qt    = Xs + 3 * PL;             // [bh][t][d] bf16, pre-scaled
  short* KtHi  = Qt + PL;
  short* KtLo  = KtHi + PL;
  short* VHi   = KtLo + PL;               // [bh][d][t] bf16
  short* Wsp   = VHi + PL;                // [4][2][E][E] bf16
  float* maskS = (float*)(Wsp + 4 * 2 * EDIM * EDIM);  // [s/4][t][4] fp32
  float* Lh    = maskS + (size_t)TDIM * TDIM;          // [4][bh][t]
  unsigned short* pp0 = (unsigned short*)Xs;  // partials overlay dead Xs
  unsigned short* pp1 = pp0 + PL;
  unsigned short* pp2 = pp1 + PL;
  // pp3 in FRESH ws (not d_out): fused proj8 writes Of while other blocks
  // still read pp3 -> overlaying d_out would race. ws usage: 34 -> 38 MB.
  unsigned short* pp3 = (unsigned short*)(Lh + (size_t)4 * NBH * TDIM);

  dim3 bb(256);
  hipLaunchKernelGGL(prepare, dim3(2048), bb, 0, stream,
                     Wq, Wk, Wv, Wo, msk, query, key, value, Wsp, maskS, Xs);
  hipLaunchKernelGGL(proj, dim3(16, 4, 24), bb, 0, stream,
                     Xs, Wsp, bq, bk, bv, bo, Qt, KtHi, KtLo, VHi,
                     (float*)nullptr, 0, pp0, pp1, pp2, pp3, Lh);
  hipLaunchKernelGGL(flash6, dim3(64, 8, 4), bb, 0, stream,
                     Qt, KtHi, KtLo, VHi, maskS, pp0, pp1, pp2, pp3, Lh);
  hipLaunchKernelGGL(proj, dim3(16, 4, 8), bb, 0, stream,
                     Xs, Wsp, bq, bk, bv, bo, Qt, KtHi, KtLo, VHi, out, 3,
                     pp0, pp1, pp2, pp3, Lh);
}

// Round 10
// 156.004 us; speedup vs baseline: 1.0402x; 1.0402x over previous
//
#include <hip/hip_runtime.h>
#include <hip/hip_bf16.h>

#define EDIM 256
#define TDIM 1024
#define NHEAD 8
#define HDIM 32
#define NBATCH 8
#define NBH 64
#define INV_LN2 1.4426950408889634f
#define SCALE2 (0.17677669529663687f * 1.4426950408889634f)  // hd^-0.5 / ln2

typedef __attribute__((ext_vector_type(8))) short short8;
typedef __attribute__((ext_vector_type(4))) short short4v;
typedef __attribute__((ext_vector_type(4))) float f32x4;

__device__ __forceinline__ f32x4 mfma16(short8 a, short8 b, f32x4 c) {
  return __builtin_amdgcn_mfma_f32_16x16x32_bf16(a, b, c, 0, 0, 0);
}
__device__ __forceinline__ float bf2f(short h) {
  return __uint_as_float(((unsigned)(unsigned short)h) << 16);
}
__device__ __forceinline__ short f2bf1(float x) {
  unsigned u = __float_as_uint(x);
  u = (u + 0x7fffu + ((u >> 16) & 1u)) >> 16;
  return (short)u;
}
__device__ __forceinline__ short4v packbf4(float a, float b, float c, float d) {
  __hip_bfloat162 x = __float22bfloat162_rn(make_float2(a, b));
  __hip_bfloat162 y = __float22bfloat162_rn(make_float2(c, d));
  unsigned ux, uy;
  __builtin_memcpy(&ux, &x, 4);
  __builtin_memcpy(&uy, &y, 4);
  short4v r;
  r[0] = (short)(ux & 0xffffu); r[1] = (short)(ux >> 16);
  r[2] = (short)(uy & 0xffffu); r[3] = (short)(uy >> 16);
  return r;
}
// Raw v_exp_f32 (no libm denorm/range fixup). Valid: args statically
// bounded ~15 << 126. (R4 ablation: halved VALUBusy, time ~flat -> kernel
// is VMEM-bound, not VALU-bound.)
__device__ __forceinline__ float fexp2(float x) {
#if __has_builtin(__builtin_amdgcn_exp2f)
  return __builtin_amdgcn_exp2f(x);
#else
  return exp2f(x);
#endif
}

// ---------------------------------------------------------------------------
// prepare (2048 blocks):
//   blk 0..255   : split 4 weight mats -> bf16 hi/lo
//   blk 256..511 : mask[t][s] -> maskS[s/4][t][4] * INV_LN2 (LDS transpose,
//                  writes 1 KB-contiguous per wave)
//   blk 512..2047: split q/k/v [B][E][T] fp32 -> Xs[tensor][b][t][e] bf16 hi
//                  (LDS transpose; both global phases coalesced)
// ---------------------------------------------------------------------------
__global__ __launch_bounds__(256) void prepare(
    const float* __restrict__ w0, const float* __restrict__ w1,
    const float* __restrict__ w2, const float* __restrict__ w3,
    const float* __restrict__ mask, const float* __restrict__ qin,
    const float* __restrict__ kin, const float* __restrict__ vin,
    short* __restrict__ wsp, float* __restrict__ maskS,
    short* __restrict__ Xs)
{
  const int blk = blockIdx.x;
  const int tid = threadIdx.x;
  __shared__ float Tl[64][65];

  if (blk < 256) {
    const int z = blk >> 6, chunk = blk & 63;
    const float* W = (z == 0) ? w0 : (z == 1) ? w1 : (z == 2) ? w2 : w3;
    short* hi = wsp + (size_t)z * 2 * EDIM * EDIM;
    short* lo = hi + EDIM * EDIM;
    const int idx = chunk * 1024 + tid * 4;
    float4 v = *(const float4*)&W[idx];
    short4v h = packbf4(v.x, v.y, v.z, v.w);
    short4v l = packbf4(v.x - bf2f(h[0]), v.y - bf2f(h[1]),
                        v.z - bf2f(h[2]), v.w - bf2f(h[3]));
    *(short4v*)&hi[idx] = h;
    *(short4v*)&lo[idx] = l;
  } else if (blk < 512) {
    const int i = blk - 256;
    const int t0 = (i >> 4) * 64, s0 = (i & 15) * 64;
    const int r = tid >> 2, c = (tid & 3) * 16;
#pragma unroll
    for (int g = 0; g < 4; ++g) {
      float4 v = *(const float4*)&mask[(size_t)(t0 + r) * TDIM + s0 + c + 4 * g];
      Tl[c + 4 * g + 0][r] = v.x * INV_LN2;
      Tl[c + 4 * g + 1][r] = v.y * INV_LN2;
      Tl[c + 4 * g + 2][r] = v.z * INV_LN2;
      Tl[c + 4 * g + 3][r] = v.w * INV_LN2;
    }
    __syncthreads();
    const int sql = tid >> 6, tl = tid & 63;
#pragma unroll
    for (int g = 0; g < 4; ++g) {
      const int sq = g * 4 + sql;       // s-quad within tile, 0..15
      float4 o;
      o.x = Tl[sq * 4 + 0][tl];
      o.y = Tl[sq * 4 + 1][tl];
      o.z = Tl[sq * 4 + 2][tl];
      o.w = Tl[sq * 4 + 3][tl];
      *(float4*)&maskS[(size_t)(s0 / 4 + sq) * 4096 + (size_t)(t0 + tl) * 4] = o;
    }
  } else {
    const int bz = blk - 512;
    const int tt = bz & 15, ee = (bz >> 4) & 3, tb = bz >> 6;  // tb 0..23
    const float* src = ((tb >> 3) == 0) ? qin : ((tb >> 3) == 1) ? kin : vin;
    const int b = tb & 7;
    const int t0 = tt * 64, e0 = ee * 64;
    const float* s = src + (size_t)b * EDIM * TDIM;
    const int tl = tid & 63, er = (tid >> 6) * 16;
#pragma unroll
    for (int i = 0; i < 16; ++i)
      Tl[tl][er + i] = s[(size_t)(e0 + er + i) * TDIM + t0 + tl];
    __syncthreads();
    const int rt = tid >> 2, seg = (tid & 3) * 16;
    float v[16];
#pragma unroll
    for (int i = 0; i < 16; ++i) v[i] = Tl[rt][seg + i];
    short* dst = Xs + ((size_t)tb * TDIM + t0 + rt) * EDIM + e0 + seg;
#pragma unroll
    for (int i = 0; i < 4; ++i)
      *(short4v*)&dst[4 * i] =
          packbf4(v[4 * i], v[4 * i + 1], v[4 * i + 2], v[4 * i + 3]);
  }
}

// ---------------------------------------------------------------------------
// proj: C = W @ X + bias, X pre-split bf16 [.][t][e], W bf16 hi/lo.
// 64m x 64n block, K=256 whole: W-frags in registers, X staged as one flat
// 32 KB XOR-swizzled copy -> single barrier. 2-pass split MFMA.
// tensor: 0=Q ([bh][t][d] bf16, *SCALE2), 1=K hi/lo, 2=V ([bh][d][t] bf16),
// 3=final (fp32 [b][E][T]).
// R10 NOTE: R9's fused-merge variant (merge4 folded into the tensor==3
// stage) REGRESSED (+3 us e2e): its scalar stride-512B ds_write_b16 scatter
// is ~16-way bank-conflicted (conflict counter +1M). Separate merge4's
// padded-LDS transpose is cheaper. Reverted.
// ---------------------------------------------------------------------------
__global__ __launch_bounds__(256, 4) void proj(
    const short* __restrict__ Xbase, const short* __restrict__ wsp,
    const float* __restrict__ b0, const float* __restrict__ b1,
    const float* __restrict__ b2, const float* __restrict__ b3,
    short* __restrict__ Qt, short* __restrict__ KtHi, short* __restrict__ KtLo,
    short* __restrict__ VHi, float* __restrict__ Of, int tbase)
{
  const int z = blockIdx.z;
  const int tloc = z >> 3;
  const int tensor = tbase + tloc;
  const int batch = z & 7;
  const int m0 = blockIdx.y * 64;
  const int n0 = blockIdx.x * 64;
  const int tid = threadIdx.x;
  const int w = tid >> 6, lane = tid & 63, q = lane >> 4, l16 = lane & 15;

  const float* bias = (tensor == 0) ? b0 : (tensor == 1) ? b1
                      : (tensor == 2) ? b2 : b3;
  const short* Wh = wsp + (size_t)tensor * 2 * EDIM * EDIM;
  const short* Wl = Wh + EDIM * EDIM;
  const short* Xt = Xbase + ((size_t)(tloc * NBATCH + batch) * TDIM + n0) * EDIM;

  __shared__ __align__(16) short Xl[64 * 256];  // 32 KB, XOR-swizzled [t][e]

  short8 ah[8], al[8];
  {
    const short* wrh = Wh + (size_t)(m0 + 16 * w + l16) * EDIM + q * 8;
    const short* wrl = Wl + (size_t)(m0 + 16 * w + l16) * EDIM + q * 8;
#pragma unroll
    for (int c = 0; c < 8; ++c) {
      ah[c] = *(const short8*)&wrh[c * 32];
      al[c] = *(const short8*)&wrl[c * 32];
    }
  }
#pragma unroll
  for (int k2 = 0; k2 < 8; ++k2) {
    const int tl = k2 * 8 + (tid >> 5);
    const int e8 = tid & 31;
    short8 vv = *(const short8*)&Xt[(size_t)k2 * 2048 + tid * 8];
    *(short8*)&Xl[tl * 256 + ((e8 ^ (tl & 7)) << 3)] = vv;
  }
  __syncthreads();

  f32x4 acc[4] = {};
  const int lm = l16 & 7;
#pragma unroll
  for (int c = 0; c < 8; ++c) {
#pragma unroll
    for (int j = 0; j < 4; ++j) {
      short8 bf = *(const short8*)&Xl[(16 * j + l16) * 256 +
                                      (((c * 4 + q) ^ lm) << 3)];
      acc[j] = mfma16(ah[c], bf, acc[j]);
      acc[j] = mfma16(al[c], bf, acc[j]);
    }
  }

  if (tensor == 3) {
#pragma unroll
    for (int j = 0; j < 4; ++j) {
      const int n = n0 + 16 * j + l16;
#pragma unroll
      for (int r = 0; r < 4; ++r) {
        const int m = m0 + 16 * w + 4 * q + r;
        Of[((size_t)batch * EDIM + m) * TDIM + n] = acc[j][r] + bias[m];
      }
    }
    return;
  }
  if (tensor == 2) {
#pragma unroll
    for (int j = 0; j < 4; ++j) {
      const int n = n0 + 16 * j + l16;
#pragma unroll
      for (int r = 0; r < 4; ++r) {
        const int m = m0 + 16 * w + 4 * q + r;
        VHi[((size_t)batch * EDIM + m) * TDIM + n] = f2bf1(acc[j][r] + bias[m]);
      }
    }
    return;
  }
  __syncthreads();
  float (*Lt)[68] = (float (*)[68])Xl;  // 17408 B <= 32768
#pragma unroll
  for (int j = 0; j < 4; ++j) {
    const int mb = m0 + 16 * w + 4 * q;
    float4 v4;
    v4.x = acc[j][0] + bias[mb + 0];
    v4.y = acc[j][1] + bias[mb + 1];
    v4.z = acc[j][2] + bias[mb + 2];
    v4.w = acc[j][3] + bias[mb + 3];
    if (tensor == 0) { v4.x *= SCALE2; v4.y *= SCALE2; v4.z *= SCALE2; v4.w *= SCALE2; }
    *(float4*)&Lt[16 * j + l16][16 * w + 4 * q] = v4;
  }
  __syncthreads();
  {
    const int tl = tid >> 2;
    const int seg = (tid & 3) * 16;
    const int ch = m0 + seg;
    const int bh = batch * NHEAD + (ch >> 5);
    const int d0 = ch & 31;
    const size_t o = ((size_t)bh * TDIM + n0 + tl) * HDIM + d0;
    float v[16];
#pragma unroll
    for (int i = 0; i < 16; ++i) v[i] = Lt[tl][seg + i];
    if (tensor == 0) {
#pragma unroll
      for (int i = 0; i < 4; ++i)
        *(short4v*)&Qt[o + 4 * i] =
            packbf4(v[4 * i], v[4 * i + 1], v[4 * i + 2], v[4 * i + 3]);
    } else {
#pragma unroll
      for (int i = 0; i < 4; ++i) {
        short4v h = packbf4(v[4 * i], v[4 * i + 1], v[4 * i + 2], v[4 * i + 3]);
        short4v l = packbf4(v[4 * i + 0] - bf2f(h[0]), v[4 * i + 1] - bf2f(h[1]),
                            v[4 * i + 2] - bf2f(h[2]), v[4 * i + 3] - bf2f(h[3]));
        *(short4v*)&KtHi[o + 4 * i] = h;
        *(short4v*)&KtLo[o + 4 * i] = l;
      }
    }
  }
}

// ---------------------------------------------------------------------------
// flash6: transposed flash, s-split x4, NO max-tracking (scores statically
// bounded). p = exp2(s+m), l = sum(p); O stored UNNORMALIZED bf16 + l per
// quarter. Ps SINGLE-buffered (per-wave, DS in-order -> WAR-safe).
// K hi/lo AND V staged in LDS once per block (R8: K-LDS -10%; R10: V-LDS —
// V is the last 4x-redundant stream, 134 MB; vh_p had no w dependence).
// V granule-XOR-swizzle g' = g ^ (d&7): V rows are 512 B so the row index
// contributes nothing to bank selection; unswizzled all 64 lanes hit 4
// banks (2x floor). Swizzle restores uniform 8 accesses/bank.
// K-LDS reads are ALREADY at the b128 bandwidth floor (uniform coverage) —
// audited, no swizzle needed. Mask (64x bh-redundant across blocks, not
// within) stays as hoisted register loads.
// LDS 66 KB; measured residency is 2 blocks/CU (register-bound), and
// 2x66=132<=160 -> no occupancy cost. Tripwire: occupancy <20% => was
// 3-block LDS-bound, revert V-LDS.
// History: (256,8) spills; (256,5)/(256,3) alone no-op; setprio -5us;
// fexp2 neutral; 20-load hoist -6%; +fence 0%; K-LDS -10% (47->43.5).
// ---------------------------------------------------------------------------
__global__ __launch_bounds__(256, 3) void flash6(
    const short* __restrict__ Qt, const short* __restrict__ KtHi,
    const short* __restrict__ KtLo, const short* __restrict__ VHi,
    const float* __restrict__ maskS, unsigned short* __restrict__ p0,
    unsigned short* __restrict__ p1, unsigned short* __restrict__ p2,
    unsigned short* __restrict__ p3, float* __restrict__ Lh)
{
  const int tid = threadIdx.x;
  const int w = tid >> 6, lane = tid & 63, q = lane >> 4, l16 = lane & 15;
  const int bh = blockIdx.x;
  const int t0 = blockIdx.y * 128 + w * 32;
  const int quarter = blockIdx.z;
  const int sbase = quarter * 256;

  __shared__ __align__(16) short KhS[8192];      // K hi [256 s][32 d], 16 KB
  __shared__ __align__(16) short KlS[8192];      // K lo, 16 KB
  __shared__ __align__(16) short VS[8192];       // V [32 d][256 s] swz, 16 KB
  __shared__ __align__(16) short Ps[4][32][72];  // per-wave P^T, 18 KB

  // ---- cooperative K+V stage: all 4 waves share one copy ----
  {
    const short* kgh = KtHi + (size_t)bh * TDIM * HDIM + (size_t)sbase * HDIM;
    const short* kgl = KtLo + (size_t)bh * TDIM * HDIM + (size_t)sbase * HDIM;
    const short* vgl = VHi + (size_t)bh * HDIM * TDIM + sbase;
#pragma unroll
    for (int r = 0; r < 4; ++r) {
      *(short8*)&KhS[r * 2048 + tid * 8] =
          *(const short8*)&kgh[r * 2048 + tid * 8];
      *(short8*)&KlS[r * 2048 + tid * 8] =
          *(const short8*)&kgl[r * 2048 + tid * 8];
      const int idx = r * 256 + tid;   // 0..1023
      const int d = idx >> 5;          // 0..31
      const int g = idx & 31;          // 16B granule within 512B row
      const int gp = (g & 24) | ((g ^ d) & 7);
      *(short8*)&VS[d * 256 + gp * 8] =
          *(const short8*)&vgl[(size_t)d * TDIM + g * 8];
    }
  }

  const short* qb = Qt + (size_t)bh * TDIM * HDIM;
  const float* m_p = maskS + ((size_t)(sbase >> 2) + q) * 4096 +
                     (size_t)(t0 + l16) * 4;

  short8 qf0 = *(const short8*)&qb[(size_t)(t0 + l16) * HDIM + q * 8];
  short8 qf1 = *(const short8*)&qb[(size_t)(t0 + 16 + l16) * HDIM + q * 8];

  __syncthreads();  // K+V staged; no further barriers (Ps is per-wave)

  float ls[2] = {0.f, 0.f};
  f32x4 oacc[2][2] = {};  // [d-tile][nt]
  const int vswz = l16 & 7;

#pragma unroll
  for (int it = 0; it < 4; ++it) {
    const float* m_i = m_p + it * 65536;

    // ---- mask loads (S^T init) up front ----
    float4 ma[4], mb[4];
#pragma unroll
    for (int mt = 0; mt < 4; ++mt) {
      ma[mt] = *(const float4*)(m_i + (size_t)mt * 16384);
      mb[mt] = *(const float4*)(m_i + (size_t)mt * 16384 + 64);
    }

    // ---- S^T = mask + K^T Q (K fragments from LDS) ----
    f32x4 sc[4][2];
#pragma unroll
    for (int mt = 0; mt < 4; ++mt) {
      sc[mt][0] = f32x4{ma[mt].x, ma[mt].y, ma[mt].z, ma[mt].w};
      sc[mt][1] = f32x4{mb[mt].x, mb[mt].y, mb[mt].z, mb[mt].w};
    }
#pragma unroll
    for (int mt = 0; mt < 4; ++mt) {
      const int srow = (64 * it + 16 * mt + l16) * 32 + q * 8;
      short8 kh = *(const short8*)&KhS[srow];
      short8 kl = *(const short8*)&KlS[srow];
      sc[mt][0] = mfma16(kh, qf0, sc[mt][0]);
      sc[mt][0] = mfma16(kl, qf0, sc[mt][0]);
      sc[mt][1] = mfma16(kh, qf1, sc[mt][1]);
      sc[mt][1] = mfma16(kl, qf1, sc[mt][1]);
    }
    // ---- p = exp2(s); tree-sum into per-lane ls ----
#pragma unroll
    for (int nt = 0; nt < 2; ++nt) {
      float p[16];
#pragma unroll
      for (int mt = 0; mt < 4; ++mt)
#pragma unroll
        for (int r = 0; r < 4; ++r) p[4 * mt + r] = fexp2(sc[mt][nt][r]);
      ls[nt] += (((p[0] + p[1]) + (p[2] + p[3])) +
                 ((p[4] + p[5]) + (p[6] + p[7]))) +
                (((p[8] + p[9]) + (p[10] + p[11])) +
                 ((p[12] + p[13]) + (p[14] + p[15])));
#pragma unroll
      for (int mt = 0; mt < 4; ++mt)
        *(short4v*)&Ps[w][16 * nt + l16][16 * mt + 4 * q] =
            packbf4(p[4 * mt], p[4 * mt + 1], p[4 * mt + 2], p[4 * mt + 3]);
    }
    // ---- O^T += V P^T (V fragments from swizzled LDS) ----
#pragma unroll
    for (int c = 0; c < 2; ++c) {
      short8 pf0 = *(const short8*)&Ps[w][l16][32 * c + 8 * q];
      short8 pf1 = *(const short8*)&Ps[w][16 + l16][32 * c + 8 * q];
#pragma unroll
      for (int dt = 0; dt < 2; ++dt) {
        const int gsw = 8 * it + ((4 * c + q) ^ vswz);
        short8 vh = *(const short8*)&VS[(16 * dt + l16) * 256 + gsw * 8];
        oacc[dt][0] = mfma16(vh, pf0, oacc[dt][0]);
        oacc[dt][1] = mfma16(vh, pf1, oacc[dt][1]);
      }
    }
  }

  ls[0] += __shfl_xor(ls[0], 16);
  ls[0] += __shfl_xor(ls[0], 32);
  ls[1] += __shfl_xor(ls[1], 16);
  ls[1] += __shfl_xor(ls[1], 32);

  unsigned short* Op = (quarter == 0) ? p0 : (quarter == 1) ? p1
                       : (quarter == 2) ? p2 : p3;
#pragma unroll
  for (int nt = 0; nt < 2; ++nt) {
    const int t = t0 + 16 * nt + l16;
#pragma unroll
    for (int dt = 0; dt < 2; ++dt)
#pragma unroll
      for (int r = 0; r < 4; ++r) {
        const int d = 16 * dt + 4 * q + r;
        Op[((size_t)bh * HDIM + d) * TDIM + t] =
            (unsigned short)f2bf1(oacc[dt][nt][r]);  // unnormalized
      }
    if (q == 0)
      Lh[(size_t)quarter * NBH * TDIM + (size_t)bh * TDIM + t] = ls[nt];
  }
}

// ---------------------------------------------------------------------------
// merge4: O = (sum_q O_q) / (sum_q l_q) -> final-proj input [b][t][e] bf16.
// (Restored from R8 — fusing this into proj regressed; see proj comment.)
// ---------------------------------------------------------------------------
__global__ __launch_bounds__(256) void merge4(
    const unsigned short* __restrict__ p0, const unsigned short* __restrict__ p1,
    const unsigned short* __restrict__ p2, const unsigned short* __restrict__ p3,
    const float* __restrict__ Lh, short* __restrict__ Xm)
{
  const int b = blockIdx.z;
  const int t0 = blockIdx.x * 64;
  const int e0 = blockIdx.y * 64;
  const int tid = threadIdx.x;
  __shared__ float Lt[64][65];

  const int t = t0 + (tid & 63);
  const int eb = e0 + (tid >> 6) * 16;
  const int bh = b * NHEAD + (eb >> 5);
  const size_t mo = (size_t)bh * TDIM + t;
  const float l = Lh[mo] + Lh[65536 + mo] + Lh[131072 + mo] + Lh[196608 + mo];
  const float inv = 1.f / l;

  const size_t ro = ((size_t)b * EDIM + eb) * TDIM + t;
#pragma unroll
  for (int i = 0; i < 16; ++i) {
    const size_t o = ro + (size_t)i * TDIM;
    const float v = (bf2f((short)p0[o]) + bf2f((short)p1[o]) +
                     bf2f((short)p2[o]) + bf2f((short)p3[o])) * inv;
    Lt[tid & 63][(tid >> 6) * 16 + i] = v;
  }
  __syncthreads();
  const int tl = tid >> 2, seg = (tid & 3) * 16;
  float v[16];
#pragma unroll
  for (int i = 0; i < 16; ++i) v[i] = Lt[tl][seg + i];
  short* dst = Xm + ((size_t)b * TDIM + t0 + tl) * EDIM + e0 + seg;
#pragma unroll
  for (int i = 0; i < 4; ++i)
    *(short4v*)&dst[4 * i] =
        packbf4(v[4 * i], v[4 * i + 1], v[4 * i + 2], v[4 * i + 3]);
}

// ---------------------------------------------------------------------------
extern "C" void kernel_launch(void* const* d_in, const int* in_sizes, int n_in,
                              void* d_out, int out_size, void* d_ws, size_t ws_size,
                              hipStream_t stream)
{
  const float* query = (const float*)d_in[0];
  const float* key   = (const float*)d_in[1];
  const float* value = (const float*)d_in[2];
  const float* msk   = (const float*)d_in[3];
  const float* Wq = (const float*)d_in[4];
  const float* Wk = (const float*)d_in[5];
  const float* Wv = (const float*)d_in[6];
  const float* Wo = (const float*)d_in[7];
  const float* bq = (const float*)d_in[8];
  const float* bk = (const float*)d_in[9];
  const float* bv = (const float*)d_in[10];
  const float* bo = (const float*)d_in[11];
  float* out = (float*)d_out;

  const size_t PL = (size_t)NBATCH * TDIM * EDIM;  // 2M elements
  short* Xs    = (short*)d_ws;            // 3 planes bf16 [tensor][b][t][e]
  short* Qt    = Xs + 3 * PL;             // [bh][t][d] bf16, pre-scaled
  short* KtHi  = Qt + PL;
  short* KtLo  = KtHi + PL;
  short* VHi   = KtLo + PL;               // [bh][d][t] bf16
  short* Wsp   = VHi + PL;                // [4][2][E][E] bf16
  float* maskS = (float*)(Wsp + 4 * 2 * EDIM * EDIM);  // [s/4][t][4] fp32
  float* Lh    = maskS + (size_t)TDIM * TDIM;          // [4][bh][t]
  unsigned short* pp0 = (unsigned short*)Xs;  // partials overlay dead Xs
  unsigned short* pp1 = pp0 + PL;
  unsigned short* pp2 = pp1 + PL;
  unsigned short* pp3 = (unsigned short*)d_out;  // safe: merge4 completes
  short* Xm = Qt;  // merged attention out [b][t][e] (Qt dead post-flash)

  dim3 bb(256);
  hipLaunchKernelGGL(prepare, dim3(2048), bb, 0, stream,
                     Wq, Wk, Wv, Wo, msk, query, key, value, Wsp, maskS, Xs);
  hipLaunchKernelGGL(proj, dim3(16, 4, 24), bb, 0, stream,
                     Xs, Wsp, bq, bk, bv, bo, Qt, KtHi, KtLo, VHi,
                     (float*)nullptr, 0);
  hipLaunchKernelGGL(flash6, dim3(64, 8, 4), bb, 0, stream,
                     Qt, KtHi, KtLo, VHi, maskS, pp0, pp1, pp2, pp3, Lh);
  hipLaunchKernelGGL(merge4, dim3(16, 4, 8), bb, 0, stream,
                     pp0, pp1, pp2, pp3, Lh, Xm);
  hipLaunchKernelGGL(proj, dim3(16, 4, 8), bb, 0, stream,
                     Xm, Wsp, bq, bk, bv, bo, Qt, KtHi, KtLo, VHi, out, 3);
}

// Round 11
// 153.830 us; speedup vs baseline: 1.0549x; 1.0141x over previous
//
#include <hip/hip_runtime.h>
#include <hip/hip_bf16.h>

#define EDIM 256
#define TDIM 1024
#define NHEAD 8
#define HDIM 32
#define NBATCH 8
#define NBH 64
#define INV_LN2 1.4426950408889634f
#define SCALE2 (0.17677669529663687f * 1.4426950408889634f)  // hd^-0.5 / ln2

typedef __attribute__((ext_vector_type(8))) short short8;
typedef __attribute__((ext_vector_type(4))) short short4v;
typedef __attribute__((ext_vector_type(4))) float f32x4;

__device__ __forceinline__ f32x4 mfma16(short8 a, short8 b, f32x4 c) {
  return __builtin_amdgcn_mfma_f32_16x16x32_bf16(a, b, c, 0, 0, 0);
}
__device__ __forceinline__ float bf2f(short h) {
  return __uint_as_float(((unsigned)(unsigned short)h) << 16);
}
__device__ __forceinline__ short f2bf1(float x) {
  unsigned u = __float_as_uint(x);
  u = (u + 0x7fffu + ((u >> 16) & 1u)) >> 16;
  return (short)u;
}
__device__ __forceinline__ short4v packbf4(float a, float b, float c, float d) {
  __hip_bfloat162 x = __float22bfloat162_rn(make_float2(a, b));
  __hip_bfloat162 y = __float22bfloat162_rn(make_float2(c, d));
  unsigned ux, uy;
  __builtin_memcpy(&ux, &x, 4);
  __builtin_memcpy(&uy, &y, 4);
  short4v r;
  r[0] = (short)(ux & 0xffffu); r[1] = (short)(ux >> 16);
  r[2] = (short)(uy & 0xffffu); r[3] = (short)(uy >> 16);
  return r;
}
// fp16 <-> f32 for the mask (R11): fp16 additive-mask error on the exp2 arg
// is <=2^-11*|m| -> rel err on p ~0.05%, 4x below the bf16 P-pack rounding
// (0.2%) that sets the current absmax. Halves the dominant 268 MB mask
// stream. (bf16 mask would be 0.4% -- an absmax gamble; fp16 is safe.)
__device__ __forceinline__ short f2h(float x) {
  _Float16 h = (_Float16)x;
  short s; __builtin_memcpy(&s, &h, 2); return s;
}
__device__ __forceinline__ float h2f(short x) {
  _Float16 h; __builtin_memcpy(&h, &x, 2); return (float)h;
}
// Raw v_exp_f32 (no libm denorm/range fixup). Valid: args statically
// bounded ~15 << 126. (R4 ablation: halved VALUBusy, time ~flat -> kernel
// is VMEM-bound, not VALU-bound.)
__device__ __forceinline__ float fexp2(float x) {
#if __has_builtin(__builtin_amdgcn_exp2f)
  return __builtin_amdgcn_exp2f(x);
#else
  return exp2f(x);
#endif
}

// ---------------------------------------------------------------------------
// prepare (2048 blocks):
//   blk 0..255   : split 4 weight mats -> bf16 hi/lo
//   blk 256..511 : mask[t][s] -> maskS[s/4][t][4] * INV_LN2 as FP16 (R11)
//                  (LDS transpose; writes 512B-contiguous per wave)
//   blk 512..2047: split q/k/v [B][E][T] fp32 -> Xs[tensor][b][t][e] bf16 hi
//                  (LDS transpose; both global phases coalesced)
// ---------------------------------------------------------------------------
__global__ __launch_bounds__(256) void prepare(
    const float* __restrict__ w0, const float* __restrict__ w1,
    const float* __restrict__ w2, const float* __restrict__ w3,
    const float* __restrict__ mask, const float* __restrict__ qin,
    const float* __restrict__ kin, const float* __restrict__ vin,
    short* __restrict__ wsp, float* __restrict__ maskS,
    short* __restrict__ Xs)
{
  const int blk = blockIdx.x;
  const int tid = threadIdx.x;
  __shared__ float Tl[64][65];

  if (blk < 256) {
    const int z = blk >> 6, chunk = blk & 63;
    const float* W = (z == 0) ? w0 : (z == 1) ? w1 : (z == 2) ? w2 : w3;
    short* hi = wsp + (size_t)z * 2 * EDIM * EDIM;
    short* lo = hi + EDIM * EDIM;
    const int idx = chunk * 1024 + tid * 4;
    float4 v = *(const float4*)&W[idx];
    short4v h = packbf4(v.x, v.y, v.z, v.w);
    short4v l = packbf4(v.x - bf2f(h[0]), v.y - bf2f(h[1]),
                        v.z - bf2f(h[2]), v.w - bf2f(h[3]));
    *(short4v*)&hi[idx] = h;
    *(short4v*)&lo[idx] = l;
  } else if (blk < 512) {
    const int i = blk - 256;
    const int t0 = (i >> 4) * 64, s0 = (i & 15) * 64;
    const int r = tid >> 2, c = (tid & 3) * 16;
#pragma unroll
    for (int g = 0; g < 4; ++g) {
      float4 v = *(const float4*)&mask[(size_t)(t0 + r) * TDIM + s0 + c + 4 * g];
      Tl[c + 4 * g + 0][r] = v.x * INV_LN2;
      Tl[c + 4 * g + 1][r] = v.y * INV_LN2;
      Tl[c + 4 * g + 2][r] = v.z * INV_LN2;
      Tl[c + 4 * g + 3][r] = v.w * INV_LN2;
    }
    __syncthreads();
    const int sql = tid >> 6, tl = tid & 63;
    unsigned short* mS = (unsigned short*)maskS;
#pragma unroll
    for (int g = 0; g < 4; ++g) {
      const int sq = g * 4 + sql;       // s-quad within tile, 0..15
      short4v o;
      o[0] = f2h(Tl[sq * 4 + 0][tl]);
      o[1] = f2h(Tl[sq * 4 + 1][tl]);
      o[2] = f2h(Tl[sq * 4 + 2][tl]);
      o[3] = f2h(Tl[sq * 4 + 3][tl]);
      *(short4v*)&mS[(size_t)(s0 / 4 + sq) * 4096 + (size_t)(t0 + tl) * 4] = o;
    }
  } else {
    const int bz = blk - 512;
    const int tt = bz & 15, ee = (bz >> 4) & 3, tb = bz >> 6;  // tb 0..23
    const float* src = ((tb >> 3) == 0) ? qin : ((tb >> 3) == 1) ? kin : vin;
    const int b = tb & 7;
    const int t0 = tt * 64, e0 = ee * 64;
    const float* s = src + (size_t)b * EDIM * TDIM;
    const int tl = tid & 63, er = (tid >> 6) * 16;
#pragma unroll
    for (int i = 0; i < 16; ++i)
      Tl[tl][er + i] = s[(size_t)(e0 + er + i) * TDIM + t0 + tl];
    __syncthreads();
    const int rt = tid >> 2, seg = (tid & 3) * 16;
    float v[16];
#pragma unroll
    for (int i = 0; i < 16; ++i) v[i] = Tl[rt][seg + i];
    short* dst = Xs + ((size_t)tb * TDIM + t0 + rt) * EDIM + e0 + seg;
#pragma unroll
    for (int i = 0; i < 4; ++i)
      *(short4v*)&dst[4 * i] =
          packbf4(v[4 * i], v[4 * i + 1], v[4 * i + 2], v[4 * i + 3]);
  }
}

// ---------------------------------------------------------------------------
// proj: C = W @ X + bias, X pre-split bf16 [.][t][e], W bf16 hi/lo.
// 64m x 64n block, K=256 whole: W-frags in registers, X staged as one flat
// 32 KB XOR-swizzled copy -> single barrier. 2-pass split MFMA.
// tensor: 0=Q ([bh][t][d] bf16, *SCALE2), 1=K hi/lo, 2=V ([bh][d][t] bf16),
// 3=final (fp32 [b][E][T]).
// R10 NOTE: R9's fused-merge variant (merge4 folded into the tensor==3
// stage) REGRESSED: scalar stride-512B ds_write_b16 scatter is ~16-way
// bank-conflicted AND the 4 m0-blocks each redo the same merge (4x work).
// Separate merge4 stays.
// ---------------------------------------------------------------------------
__global__ __launch_bounds__(256, 4) void proj(
    const short* __restrict__ Xbase, const short* __restrict__ wsp,
    const float* __restrict__ b0, const float* __restrict__ b1,
    const float* __restrict__ b2, const float* __restrict__ b3,
    short* __restrict__ Qt, short* __restrict__ KtHi, short* __restrict__ KtLo,
    short* __restrict__ VHi, float* __restrict__ Of, int tbase)
{
  const int z = blockIdx.z;
  const int tloc = z >> 3;
  const int tensor = tbase + tloc;
  const int batch = z & 7;
  const int m0 = blockIdx.y * 64;
  const int n0 = blockIdx.x * 64;
  const int tid = threadIdx.x;
  const int w = tid >> 6, lane = tid & 63, q = lane >> 4, l16 = lane & 15;

  const float* bias = (tensor == 0) ? b0 : (tensor == 1) ? b1
                      : (tensor == 2) ? b2 : b3;
  const short* Wh = wsp + (size_t)tensor * 2 * EDIM * EDIM;
  const short* Wl = Wh + EDIM * EDIM;
  const short* Xt = Xbase + ((size_t)(tloc * NBATCH + batch) * TDIM + n0) * EDIM;

  __shared__ __align__(16) short Xl[64 * 256];  // 32 KB, XOR-swizzled [t][e]

  short8 ah[8], al[8];
  {
    const short* wrh = Wh + (size_t)(m0 + 16 * w + l16) * EDIM + q * 8;
    const short* wrl = Wl + (size_t)(m0 + 16 * w + l16) * EDIM + q * 8;
#pragma unroll
    for (int c = 0; c < 8; ++c) {
      ah[c] = *(const short8*)&wrh[c * 32];
      al[c] = *(const short8*)&wrl[c * 32];
    }
  }
#pragma unroll
  for (int k2 = 0; k2 < 8; ++k2) {
    const int tl = k2 * 8 + (tid >> 5);
    const int e8 = tid & 31;
    short8 vv = *(const short8*)&Xt[(size_t)k2 * 2048 + tid * 8];
    *(short8*)&Xl[tl * 256 + ((e8 ^ (tl & 7)) << 3)] = vv;
  }
  __syncthreads();

  f32x4 acc[4] = {};
  const int lm = l16 & 7;
#pragma unroll
  for (int c = 0; c < 8; ++c) {
#pragma unroll
    for (int j = 0; j < 4; ++j) {
      short8 bf = *(const short8*)&Xl[(16 * j + l16) * 256 +
                                      (((c * 4 + q) ^ lm) << 3)];
      acc[j] = mfma16(ah[c], bf, acc[j]);
      acc[j] = mfma16(al[c], bf, acc[j]);
    }
  }

  if (tensor == 3) {
#pragma unroll
    for (int j = 0; j < 4; ++j) {
      const int n = n0 + 16 * j + l16;
#pragma unroll
      for (int r = 0; r < 4; ++r) {
        const int m = m0 + 16 * w + 4 * q + r;
        Of[((size_t)batch * EDIM + m) * TDIM + n] = acc[j][r] + bias[m];
      }
    }
    return;
  }
  if (tensor == 2) {
#pragma unroll
    for (int j = 0; j < 4; ++j) {
      const int n = n0 + 16 * j + l16;
#pragma unroll
      for (int r = 0; r < 4; ++r) {
        const int m = m0 + 16 * w + 4 * q + r;
        VHi[((size_t)batch * EDIM + m) * TDIM + n] = f2bf1(acc[j][r] + bias[m]);
      }
    }
    return;
  }
  __syncthreads();
  float (*Lt)[68] = (float (*)[68])Xl;  // 17408 B <= 32768
#pragma unroll
  for (int j = 0; j < 4; ++j) {
    const int mb = m0 + 16 * w + 4 * q;
    float4 v4;
    v4.x = acc[j][0] + bias[mb + 0];
    v4.y = acc[j][1] + bias[mb + 1];
    v4.z = acc[j][2] + bias[mb + 2];
    v4.w = acc[j][3] + bias[mb + 3];
    if (tensor == 0) { v4.x *= SCALE2; v4.y *= SCALE2; v4.z *= SCALE2; v4.w *= SCALE2; }
    *(float4*)&Lt[16 * j + l16][16 * w + 4 * q] = v4;
  }
  __syncthreads();
  {
    const int tl = tid >> 2;
    const int seg = (tid & 3) * 16;
    const int ch = m0 + seg;
    const int bh = batch * NHEAD + (ch >> 5);
    const int d0 = ch & 31;
    const size_t o = ((size_t)bh * TDIM + n0 + tl) * HDIM + d0;
    float v[16];
#pragma unroll
    for (int i = 0; i < 16; ++i) v[i] = Lt[tl][seg + i];
    if (tensor == 0) {
#pragma unroll
      for (int i = 0; i < 4; ++i)
        *(short4v*)&Qt[o + 4 * i] =
            packbf4(v[4 * i], v[4 * i + 1], v[4 * i + 2], v[4 * i + 3]);
    } else {
#pragma unroll
      for (int i = 0; i < 4; ++i) {
        short4v h = packbf4(v[4 * i], v[4 * i + 1], v[4 * i + 2], v[4 * i + 3]);
        short4v l = packbf4(v[4 * i + 0] - bf2f(h[0]), v[4 * i + 1] - bf2f(h[1]),
                            v[4 * i + 2] - bf2f(h[2]), v[4 * i + 3] - bf2f(h[3]));
        *(short4v*)&KtHi[o + 4 * i] = h;
        *(short4v*)&KtLo[o + 4 * i] = l;
      }
    }
  }
}

// ---------------------------------------------------------------------------
// flash6: transposed flash, s-split x4, NO max-tracking (scores statically
// bounded). p = exp2(s+m), l = sum(p); O stored UNNORMALIZED bf16 + l per
// quarter. Ps SINGLE-buffered (per-wave, DS in-order -> WAR-safe).
// K hi/lo AND V staged in LDS once per block (R8 K-LDS -10%; R10 V-LDS -7%;
// both were 4x-redundant across the block's waves). V granule-XOR-swizzle
// restores uniform 8 req/bank. Mask: 64x bh-redundant ACROSS blocks
// (structural, not LDS-shareable) -> R11 stores it FP16 (268->134 MB, the
// dominant remaining stream; err on exp2-arg <=2^-11 -> ~0.05% on p, 4x
// below bf16 P-pack rounding -> absmax unchanged).
// LDS 66 KB. History: (256,8) spills; (256,5)/(256,3) alone no-op;
// setprio -5us; fexp2 neutral; 20-load hoist -6%; +fence 0%;
// K-LDS -10% (47->43.5); V-LDS -7% (<43.4).
// ---------------------------------------------------------------------------
__global__ __launch_bounds__(256, 3) void flash6(
    const short* __restrict__ Qt, const short* __restrict__ KtHi,
    const short* __restrict__ KtLo, const short* __restrict__ VHi,
    const float* __restrict__ maskS, unsigned short* __restrict__ p0,
    unsigned short* __restrict__ p1, unsigned short* __restrict__ p2,
    unsigned short* __restrict__ p3, float* __restrict__ Lh)
{
  const int tid = threadIdx.x;
  const int w = tid >> 6, lane = tid & 63, q = lane >> 4, l16 = lane & 15;
  const int bh = blockIdx.x;
  const int t0 = blockIdx.y * 128 + w * 32;
  const int quarter = blockIdx.z;
  const int sbase = quarter * 256;

  __shared__ __align__(16) short KhS[8192];      // K hi [256 s][32 d], 16 KB
  __shared__ __align__(16) short KlS[8192];      // K lo, 16 KB
  __shared__ __align__(16) short VS[8192];       // V [32 d][256 s] swz, 16 KB
  __shared__ __align__(16) short Ps[4][32][72];  // per-wave P^T, 18 KB

  // ---- cooperative K+V stage: all 4 waves share one copy ----
  {
    const short* kgh = KtHi + (size_t)bh * TDIM * HDIM + (size_t)sbase * HDIM;
    const short* kgl = KtLo + (size_t)bh * TDIM * HDIM + (size_t)sbase * HDIM;
    const short* vgl = VHi + (size_t)bh * HDIM * TDIM + sbase;
#pragma unroll
    for (int r = 0; r < 4; ++r) {
      *(short8*)&KhS[r * 2048 + tid * 8] =
          *(const short8*)&kgh[r * 2048 + tid * 8];
      *(short8*)&KlS[r * 2048 + tid * 8] =
          *(const short8*)&kgl[r * 2048 + tid * 8];
      const int idx = r * 256 + tid;   // 0..1023
      const int d = idx >> 5;          // 0..31
      const int g = idx & 31;          // 16B granule within 512B row
      const int gp = (g & 24) | ((g ^ d) & 7);
      *(short8*)&VS[d * 256 + gp * 8] =
          *(const short8*)&vgl[(size_t)d * TDIM + g * 8];
    }
  }

  const short* qb = Qt + (size_t)bh * TDIM * HDIM;
  const unsigned short* m_p = (const unsigned short*)maskS +
                              ((size_t)(sbase >> 2) + q) * 4096 +
                              (size_t)(t0 + l16) * 4;

  short8 qf0 = *(const short8*)&qb[(size_t)(t0 + l16) * HDIM + q * 8];
  short8 qf1 = *(const short8*)&qb[(size_t)(t0 + 16 + l16) * HDIM + q * 8];

  __syncthreads();  // K+V staged; no further barriers (Ps is per-wave)

  float ls[2] = {0.f, 0.f};
  f32x4 oacc[2][2] = {};  // [d-tile][nt]
  const int vswz = l16 & 7;

#pragma unroll
  for (int it = 0; it < 4; ++it) {
    const unsigned short* m_i = m_p + it * 65536;

    // ---- mask loads (fp16, 8B each) up front ----
    short4v ma[4], mb[4];
#pragma unroll
    for (int mt = 0; mt < 4; ++mt) {
      ma[mt] = *(const short4v*)(m_i + (size_t)mt * 16384);
      mb[mt] = *(const short4v*)(m_i + (size_t)mt * 16384 + 64);
    }

    // ---- S^T = mask + K^T Q (K fragments from LDS) ----
    f32x4 sc[4][2];
#pragma unroll
    for (int mt = 0; mt < 4; ++mt) {
      sc[mt][0] = f32x4{h2f(ma[mt][0]), h2f(ma[mt][1]),
                        h2f(ma[mt][2]), h2f(ma[mt][3])};
      sc[mt][1] = f32x4{h2f(mb[mt][0]), h2f(mb[mt][1]),
                        h2f(mb[mt][2]), h2f(mb[mt][3])};
    }
#pragma unroll
    for (int mt = 0; mt < 4; ++mt) {
      const int srow = (64 * it + 16 * mt + l16) * 32 + q * 8;
      short8 kh = *(const short8*)&KhS[srow];
      short8 kl = *(const short8*)&KlS[srow];
      sc[mt][0] = mfma16(kh, qf0, sc[mt][0]);
      sc[mt][0] = mfma16(kl, qf0, sc[mt][0]);
      sc[mt][1] = mfma16(kh, qf1, sc[mt][1]);
      sc[mt][1] = mfma16(kl, qf1, sc[mt][1]);
    }
    // ---- p = exp2(s); tree-sum into per-lane ls ----
#pragma unroll
    for (int nt = 0; nt < 2; ++nt) {
      float p[16];
#pragma unroll
      for (int mt = 0; mt < 4; ++mt)
#pragma unroll
        for (int r = 0; r < 4; ++r) p[4 * mt + r] = fexp2(sc[mt][nt][r]);
      ls[nt] += (((p[0] + p[1]) + (p[2] + p[3])) +
                 ((p[4] + p[5]) + (p[6] + p[7]))) +
                (((p[8] + p[9]) + (p[10] + p[11])) +
                 ((p[12] + p[13]) + (p[14] + p[15])));
#pragma unroll
      for (int mt = 0; mt < 4; ++mt)
        *(short4v*)&Ps[w][16 * nt + l16][16 * mt + 4 * q] =
            packbf4(p[4 * mt], p[4 * mt + 1], p[4 * mt + 2], p[4 * mt + 3]);
    }
    // ---- O^T += V P^T (V fragments from swizzled LDS) ----
#pragma unroll
    for (int c = 0; c < 2; ++c) {
      short8 pf0 = *(const short8*)&Ps[w][l16][32 * c + 8 * q];
      short8 pf1 = *(const short8*)&Ps[w][16 + l16][32 * c + 8 * q];
#pragma unroll
      for (int dt = 0; dt < 2; ++dt) {
        const int gsw = 8 * it + ((4 * c + q) ^ vswz);
        short8 vh = *(const short8*)&VS[(16 * dt + l16) * 256 + gsw * 8];
        oacc[dt][0] = mfma16(vh, pf0, oacc[dt][0]);
        oacc[dt][1] = mfma16(vh, pf1, oacc[dt][1]);
      }
    }
  }

  ls[0] += __shfl_xor(ls[0], 16);
  ls[0] += __shfl_xor(ls[0], 32);
  ls[1] += __shfl_xor(ls[1], 16);
  ls[1] += __shfl_xor(ls[1], 32);

  unsigned short* Op = (quarter == 0) ? p0 : (quarter == 1) ? p1
                       : (quarter == 2) ? p2 : p3;
#pragma unroll
  for (int nt = 0; nt < 2; ++nt) {
    const int t = t0 + 16 * nt + l16;
#pragma unroll
    for (int dt = 0; dt < 2; ++dt)
#pragma unroll
      for (int r = 0; r < 4; ++r) {
        const int d = 16 * dt + 4 * q + r;
        Op[((size_t)bh * HDIM + d) * TDIM + t] =
            (unsigned short)f2bf1(oacc[dt][nt][r]);  // unnormalized
      }
    if (q == 0)
      Lh[(size_t)quarter * NBH * TDIM + (size_t)bh * TDIM + t] = ls[nt];
  }
}

// ---------------------------------------------------------------------------
// merge4: O = (sum_q O_q) / (sum_q l_q) -> final-proj input [b][t][e] bf16.
// ---------------------------------------------------------------------------
__global__ __launch_bounds__(256) void merge4(
    const unsigned short* __restrict__ p0, const unsigned short* __restrict__ p1,
    const unsigned short* __restrict__ p2, const unsigned short* __restrict__ p3,
    const float* __restrict__ Lh, short* __restrict__ Xm)
{
  const int b = blockIdx.z;
  const int t0 = blockIdx.x * 64;
  const int e0 = blockIdx.y * 64;
  const int tid = threadIdx.x;
  __shared__ float Lt[64][65];

  const int t = t0 + (tid & 63);
  const int eb = e0 + (tid >> 6) * 16;
  const int bh = b * NHEAD + (eb >> 5);
  const size_t mo = (size_t)bh * TDIM + t;
  const float l = Lh[mo] + Lh[65536 + mo] + Lh[131072 + mo] + Lh[196608 + mo];
  const float inv = 1.f / l;

  const size_t ro = ((size_t)b * EDIM + eb) * TDIM + t;
#pragma unroll
  for (int i = 0; i < 16; ++i) {
    const size_t o = ro + (size_t)i * TDIM;
    const float v = (bf2f((short)p0[o]) + bf2f((short)p1[o]) +
                     bf2f((short)p2[o]) + bf2f((short)p3[o])) * inv;
    Lt[tid & 63][(tid >> 6) * 16 + i] = v;
  }
  __syncthreads();
  const int tl = tid >> 2, seg = (tid & 3) * 16;
  float v[16];
#pragma unroll
  for (int i = 0; i < 16; ++i) v[i] = Lt[tl][seg + i];
  short* dst = Xm + ((size_t)b * TDIM + t0 + tl) * EDIM + e0 + seg;
#pragma unroll
  for (int i = 0; i < 4; ++i)
    *(short4v*)&dst[4 * i] =
        packbf4(v[4 * i], v[4 * i + 1], v[4 * i + 2], v[4 * i + 3]);
}

// ---------------------------------------------------------------------------
extern "C" void kernel_launch(void* const* d_in, const int* in_sizes, int n_in,
                              void* d_out, int out_size, void* d_ws, size_t ws_size,
                              hipStream_t stream)
{
  const float* query = (const float*)d_in[0];
  const float* key   = (const float*)d_in[1];
  const float* value = (const float*)d_in[2];
  const float* msk   = (const float*)d_in[3];
  const float* Wq = (const float*)d_in[4];
  const float* Wk = (const float*)d_in[5];
  const float* Wv = (const float*)d_in[6];
  const float* Wo = (const float*)d_in[7];
  const float* bq = (const float*)d_in[8];
  const float* bk = (const float*)d_in[9];
  const float* bv = (const float*)d_in[10];
  const float* bo = (const float*)d_in[11];
  float* out = (float*)d_out;

  const size_t PL = (size_t)NBATCH * TDIM * EDIM;  // 2M elements
  short* Xs    = (short*)d_ws;            // 3 planes bf16 [tensor][b][t][e]
  short* Qt    = Xs + 3 * PL;             // [bh][t][d] bf16, pre-scaled
  short* KtHi  = Qt + PL;
  short* KtLo  = KtHi + PL;
  short* VHi   = KtLo + PL;               // [bh][d][t] bf16
  short* Wsp   = VHi + PL;                // [4][2][E][E] bf16
  float* maskS = (float*)(Wsp + 4 * 2 * EDIM * EDIM);  // fp16 in fp32 slot
  float* Lh    = maskS + (size_t)TDIM * TDIM;          // [4][bh][t]
  unsigned short* pp0 = (unsigned short*)Xs;  // partials overlay dead Xs
  unsigned short* pp1 = pp0 + PL;
  unsigned short* pp2 = pp1 + PL;
  unsigned short* pp3 = (unsigned short*)d_out;  // safe: merge4 completes
  short* Xm = Qt;  // merged attention out [b][t][e] (Qt dead post-flash)

  dim3 bb(256);
  hipLaunchKernelGGL(prepare, dim3(2048), bb, 0, stream,
                     Wq, Wk, Wv, Wo, msk, query, key, value, Wsp, maskS, Xs);
  hipLaunchKernelGGL(proj, dim3(16, 4, 24), bb, 0, stream,
                     Xs, Wsp, bq, bk, bv, bo, Qt, KtHi, KtLo, VHi,
                     (float*)nullptr, 0);
  hipLaunchKernelGGL(flash6, dim3(64, 8, 4), bb, 0, stream,
                     Qt, KtHi, KtLo, VHi, maskS, pp0, pp1, pp2, pp3, Lh);
  hipLaunchKernelGGL(merge4, dim3(16, 4, 8), bb, 0, stream,
                     pp0, pp1, pp2, pp3, Lh, Xm);
  hipLaunchKernelGGL(proj, dim3(16, 4, 8), bb, 0, stream,
                     Xm, Wsp, bq, bk, bv, bo, Qt, KtHi, KtLo, VHi, out, 3);
}